// Round 6
// baseline (518.146 us; speedup 1.0000x reference)
//
#include <hip/hip_runtime.h>
#include <math.h>

// ForwardKinematics: B=524288, J=24, fp32.
// v6 (resubmit after infra failure; kernel unchanged): zero-LDS, per-chunk
// per-lane BURST stores.
// v5 post-mortem: WRITE hit exactly-ideal 151MB (dense LDS-transposed stores)
// but dur stuck at 120us: LDS 18.9KB/wave -> 2 waves/SIMD, Occupancy 18.5%,
// VALUBusy 18% -> latency-bound (fill kernels in same capture hit 6.7 TB/s).
// Insight: v2's store blowup was scalar dwords spread across the WHOLE kernel
// (lines partial for ~100us -> evicted mid-fill -> RFO + 1.9x writeback).
// Lines just need full coverage within a short window: a per-lane burst of
// 6 consecutive dwordx4 (96B contiguous per record per chunk) completes every
// line within ~30cy (one chunk-seam line/record completes ~400cy later, far
// under the ~12us L2 eviction horizon). So the LDS transpose is unnecessary:
// pack 24 position floats -> 6 float4 in registers (static unroll), burst.
// LDS=0 -> occupancy VGPR-bound (~4-5 waves/SIMD, 2-2.5x v5), no lgkmcnt
// round-trip, no bank conflicts, no barriers.

#define NB 524288
#define NJ 24
#define BLOCK 64

namespace {
constexpr int PAR[NJ] = {-1,0,0,0,1,2,3,4,5,6,7,8,9,9,9,12,13,14,16,17,18,19,20,21};
}

__global__ __launch_bounds__(BLOCK, 4)   // min 4 waves/EU -> VGPR cap 128
void ForwardKinematics_51342039056994_kernel(
    const float* __restrict__ root_q,   // (B,4)
    const float* __restrict__ root_p,   // (B,3)
    const float* __restrict__ loc_q,    // (B,24,4)
    const float* __restrict__ bones,    // (B,24)
    const float* __restrict__ rest_d,   // (24,3) uniform -> scalar loads
    float* __restrict__ out)            // (B,24,3)
{
    const int lane = threadIdx.x;                  // 0..63
    const int b = blockIdx.x * BLOCK + lane;

    float gqw[NJ], gqx[NJ], gqy[NJ], gqz[NJ];
    float gpx[NJ], gpy[NJ], gpz[NJ];

    // ---- root inputs (coalesced float4 quat + 3 dwords position) ----
    float4 rq = ((const float4*)root_q)[b];
    float rpx = root_p[b*3+0], rpy = root_p[b*3+1], rpz = root_p[b*3+2];
    {
        float inv = 1.0f / (sqrtf(rq.x*rq.x + rq.y*rq.y + rq.z*rq.z + rq.w*rq.w) + 1e-8f);
        gqw[0] = rq.x * inv; gqx[0] = rq.y * inv; gqy[0] = rq.z * inv; gqz[0] = rq.w * inv;
    }
    gpx[0] = rpx; gpy[0] = rpy; gpz[0] = rpz;

    const float4* lsrc = (const float4*)loc_q + (size_t)b * NJ;   // 24 float4/elem
    const float4* bsrc = (const float4*)(bones + (size_t)b * NJ); // 6 float4/elem
    float4* dstv = (float4*)(out + (size_t)b * 72);               // 18 float4/elem

    #define DO_JOINT(j, lqv, L)                                                 \
    {                                                                           \
        const int p_ = PAR[(j)];                                                \
        float lw = (lqv).x, lx = (lqv).y, ly = (lqv).z, lz = (lqv).w;           \
        float invn = 1.0f / (sqrtf(lw*lw + lx*lx + ly*ly + lz*lz) + 1e-8f);     \
        lw *= invn; lx *= invn; ly *= invn; lz *= invn;                         \
        const float pw  = gqw[p_], px_ = gqx[p_], py_ = gqy[p_], pz_ = gqz[p_]; \
        gqw[(j)] = pw*lw - px_*lx - py_*ly - pz_*lz;                            \
        gqx[(j)] = pw*lx + px_*lw + py_*lz - pz_*ly;                            \
        gqy[(j)] = pw*ly - px_*lz + py_*lw + pz_*lx;                            \
        gqz[(j)] = pw*lz + px_*ly - py_*lx + pz_*lw;                            \
        const float dx = rest_d[3*(j)+0];                                       \
        const float dy = rest_d[3*(j)+1];                                       \
        const float dz = rest_d[3*(j)+2];                                       \
        float tx = 2.0f*(py_*dz - pz_*dy);                                      \
        float ty = 2.0f*(pz_*dx - px_*dz);                                      \
        float tz = 2.0f*(px_*dy - py_*dx);                                      \
        float rx = dx + pw*tx + (py_*tz - pz_*ty);                              \
        float ry = dy + pw*ty + (pz_*tx - px_*tz);                              \
        float rz = dz + pw*tz + (px_*ty - py_*tx);                              \
        gpx[(j)] = gpx[p_] + rx*(L);                                            \
        gpy[(j)] = gpy[p_] + ry*(L);                                            \
        gpz[(j)] = gpz[p_] + rz*(L);                                            \
    }

    // component f (0..71) of the record: joint f/3, axis f%3 — all indices
    // fold at compile time inside the unrolled loops.
    #define COMP(f) (((f) % 3 == 0) ? gpx[(f)/3] : ((f) % 3 == 1) ? gpy[(f)/3] : gpz[(f)/3])

    // ---- prefetch chunk 0 inputs ----
    float4 lq[8];
    #pragma unroll
    for (int i = 0; i < 8; ++i) lq[i] = lsrc[i];
    float4 bq0 = bsrc[0], bq1 = bsrc[1];

    #pragma unroll
    for (int c = 0; c < 3; ++c) {
        // prefetch chunk c+1 (latency hidden under compute + store of chunk c)
        float4 nlq[8]; float4 nb0, nb1;
        if (c < 2) {
            #pragma unroll
            for (int i = 0; i < 8; ++i) nlq[i] = lsrc[8*(c+1) + i];
            nb0 = bsrc[2*(c+1) + 0];
            nb1 = bsrc[2*(c+1) + 1];
        }

        float bl[8] = {bq0.x, bq0.y, bq0.z, bq0.w, bq1.x, bq1.y, bq1.z, bq1.w};

        // ---- compute 8 joints, register-resident ----
        #pragma unroll
        for (int jj = 0; jj < 8; ++jj) {
            const int j = 8*c + jj;
            if (j > 0) DO_JOINT(j, lq[jj], bl[jj]);
        }

        // ---- burst store: pack 24 floats -> 6 float4, 96B contiguous at
        // b*288 + c*96. All 6 stores issue back-to-back: every 64B line of
        // this run is fully covered within ~30cy (chunk-seam line completes
        // next chunk, ~400cy, still far under L2 eviction horizon). ----
        #pragma unroll
        for (int i = 0; i < 6; ++i) {
            const int f = 24*c + 4*i;
            float4 v;
            v.x = COMP(f + 0);
            v.y = COMP(f + 1);
            v.z = COMP(f + 2);
            v.w = COMP(f + 3);
            dstv[c*6 + i] = v;
        }

        if (c < 2) {
            #pragma unroll
            for (int i = 0; i < 8; ++i) lq[i] = nlq[i];
            bq0 = nb0; bq1 = nb1;
        }
    }
    #undef DO_JOINT
    #undef COMP
}

extern "C" void kernel_launch(void* const* d_in, const int* in_sizes, int n_in,
                              void* d_out, int out_size, void* d_ws, size_t ws_size,
                              hipStream_t stream) {
    (void)in_sizes; (void)n_in; (void)out_size; (void)d_ws; (void)ws_size;
    const float* root_q = (const float*)d_in[0];
    const float* root_p = (const float*)d_in[1];
    const float* loc_q  = (const float*)d_in[2];
    const float* bones  = (const float*)d_in[3];
    const float* rest_d = (const float*)d_in[4];
    float* out = (float*)d_out;

    dim3 grid(NB / BLOCK);
    dim3 block(BLOCK);
    ForwardKinematics_51342039056994_kernel<<<grid, block, 0, stream>>>(
        root_q, root_p, loc_q, bones, rest_d, out);
}